// Round 12
// baseline (714.344 us; speedup 1.0000x reference)
//
#include <hip/hip_runtime.h>
#include <hip/hip_bf16.h>
#include <hip/hip_cooperative_groups.h>

namespace cg = cooperative_groups;

// ---------------- problem constants ----------------
#define N_NODES 4096
#define NE      32768           // raw edges
#define E_TOT   (NE + N_NODES)  // + self loops = 36864
#define IN_FEAT 256
#define HID     64
#define IN_HEAD 64
#define F1      4096            // IN_HEAD*HID
#define OUT_HEAD 5
#define OUT_FEAT 128
#define F2      640             // OUT_HEAD*OUT_FEAT
#define NEG_SLOPE 0.2f
#define EPS_A   1e-16f
#define ZSPLIT  8               // gemm2 split-K factor

typedef __bf16 bf16;
typedef bf16 bf16x8 __attribute__((ext_vector_type(8)));
typedef bf16 bf16x4 __attribute__((ext_vector_type(4)));
typedef float f32x4 __attribute__((ext_vector_type(4)));

// async global->LDS, 16B per lane; lds base must be wave-uniform (m104/m108)
__device__ inline void async_cp16(bf16* lds, const bf16* g) {
    __builtin_amdgcn_global_load_lds(
        (const __attribute__((address_space(1))) unsigned int*)g,
        (__attribute__((address_space(3))) unsigned int*)lds, 16, 0, 0);
}

// ---------------- MFMA GEMM body (r4 swizzle, 0 bank conflicts) -------------
template <typename TC>
__device__ __forceinline__ void gemm_body(
    const bf16* __restrict__ A, const bf16* __restrict__ BT, TC* __restrict__ Cz,
    int m0, int n0, int kbeg, int kchunk, int Ncols, int Kdim,
    bf16 (*As)[64], bf16 (*Bs)[64], int tid) {
    const int wave = tid >> 6, lane = tid & 63;
    const int quad = lane >> 4, lr = lane & 15;
    const int wm = (wave >> 1) * 64;
    const int wn = (wave & 1) * 64;
    const int srow = lane >> 3;
    const int scol = ((lane & 7) ^ srow) * 8;
    const int xk = lr & 7;

    f32x4 acc[4][4] = {};

    for (int kk = 0; kk < kchunk; kk += 64) {
        int k0 = kbeg + kk;
#pragma unroll
        for (int c = 0; c < 4; ++c) {
            int r = wave * 32 + c * 8;
            async_cp16(&As[r][0], A + (size_t)(m0 + r + srow) * Kdim + k0 + scol);
            async_cp16(&Bs[r][0], BT + (size_t)(n0 + r + srow) * Kdim + k0 + scol);
        }
        __syncthreads();
#pragma unroll
        for (int ks = 0; ks < 2; ++ks) {
            int ch = ((ks * 4 + quad) ^ xk) * 8;
            bf16x8 af[4], bfr[4];
#pragma unroll
            for (int mt = 0; mt < 4; ++mt)
                af[mt] = *(const bf16x8*)(&As[wm + mt * 16 + lr][ch]);
#pragma unroll
            for (int nt = 0; nt < 4; ++nt)
                bfr[nt] = *(const bf16x8*)(&Bs[wn + nt * 16 + lr][ch]);
#pragma unroll
            for (int mt = 0; mt < 4; ++mt)
#pragma unroll
                for (int nt = 0; nt < 4; ++nt)
                    acc[mt][nt] = __builtin_amdgcn_mfma_f32_16x16x32_bf16(
                        af[mt], bfr[nt], acc[mt][nt], 0, 0, 0);
        }
        __syncthreads();
    }

#pragma unroll
    for (int mt = 0; mt < 4; ++mt)
#pragma unroll
        for (int nt = 0; nt < 4; ++nt) {
            int row0 = m0 + wm + mt * 16 + quad * 4;
            int col = n0 + wn + nt * 16 + lr;
#pragma unroll
            for (int r = 0; r < 4; ++r)
                Cz[(size_t)(row0 + r) * Ncols + col] = (TC)acc[mt][nt][r];
        }
}

// ---------------- mega-kernel args ----------------
struct MegaArgs {
    const int* esrc; const int* edst;
    const float *x, *W1, *as1, *ad1, *b1, *W2, *as2, *ad2, *b2;
    float* out;
    bf16 *H1, *h_elu, *Hp, *xb, *W1T, *W2T, *w1s, *w1d;
    float *H2, *a_src1, *a_dst1, *a_src2, *a_dst2, *m2, *dinv2;
    int *row_start, *cursor;
    int *elist;
    int *counts;        // contiguous zero region: counts | beta | acc_out
    float *beta, *acc_out;
};

#define PB_H   144
#define PB_X   512
#define PB_W1  1024
#define PB_W2  2560
#define P1_TOT (PB_H + PB_X + PB_W1 + PB_W2 + 64)   // 4304
#define P3_G1  1024
#define P3_SC  144
#define P3_TOT (P3_G1 + P3_SC + 1024)               // 2192
#define ZWORDS (N_NODES + N_NODES * OUT_HEAD + 8 * OUT_FEAT)  // 25600

__global__ __launch_bounds__(256, 3)
void mega_kernel(MegaArgs a) {
    cg::grid_group grid = cg::this_grid();
    const int b = blockIdx.x, t = threadIdx.x;
    const int gs = gridDim.x;                 // multiple of 8
    const int wave = t >> 6, lane = t & 63;

    __shared__ alignas(16) char lds[32768];
    bf16 (*As)[64] = reinterpret_cast<bf16(*)[64]>(lds);
    bf16 (*Bs)[64] = reinterpret_cast<bf16(*)[64]>(lds + 16384);
    float (*tile)[33] = reinterpret_cast<float(*)[33]>(lds);
    int* part = reinterpret_cast<int*>(lds);
    int* pre  = reinterpret_cast<int*>(lds + 1024);
    float* buf = reinterpret_cast<float*>(lds);

    // ---- P0: zero counts|beta|acc_out ----
    for (int i = b * 256 + t; i < ZWORDS; i += gs * 256) a.counts[i] = 0;
    grid.sync();

    // ---- P1: hist | x->bf16 | W1^T | W2^T | att1-fold ----
    for (int u = b; u < P1_TOT; u += gs) {
        if (u < PB_H) {
            int e = u * 256 + t;
            if (e < E_TOT) {
                int d = (e < NE) ? a.edst[e] : (e - NE);
                atomicAdd(&a.counts[d], 1);
            }
        } else if (u < PB_H + PB_X) {
            int i = (u - PB_H) * 256 + t;
            f32x4 v0 = *(const f32x4*)(a.x + (size_t)i * 8);
            f32x4 v1 = *(const f32x4*)(a.x + (size_t)i * 8 + 4);
            bf16x8 r;
            r[0] = (bf16)v0[0]; r[1] = (bf16)v0[1]; r[2] = (bf16)v0[2]; r[3] = (bf16)v0[3];
            r[4] = (bf16)v1[0]; r[5] = (bf16)v1[1]; r[6] = (bf16)v1[2]; r[7] = (bf16)v1[3];
            *(bf16x8*)(a.xb + (size_t)i * 8) = r;
        } else if (u < PB_H + PB_X + PB_W1 + PB_W2) {
            const float* S; bf16* D; int R, C, gx, gy;
            int bb = u - PB_H - PB_X;
            if (bb < PB_W1) {
                S = a.W1; D = a.W1T; R = IN_FEAT; C = F1;
                gx = bb % (F1 / 32); gy = bb / (F1 / 32);
            } else {
                bb -= PB_W1;
                S = a.W2; D = a.W2T; R = F1; C = F2;
                gx = bb % (F2 / 32); gy = bb / (F2 / 32);
            }
            int tx = t & 31, ty = t >> 5;
            int c0 = gx * 32, r0 = gy * 32;
            __syncthreads();   // protect tile reuse across stride iterations
#pragma unroll
            for (int i = 0; i < 4; ++i)
                tile[ty + i * 8][tx] = S[(size_t)(r0 + ty + i * 8) * C + c0 + tx];
            __syncthreads();
#pragma unroll
            for (int i = 0; i < 4; ++i)
                D[(size_t)(c0 + ty + i * 8) * R + r0 + tx] = (bf16)tile[tx][ty + i * 8];
        } else {
            int id = (u - PB_H - PB_X - PB_W1 - PB_W2) * 256 + t;
            int k = id >> 6, h = id & 63;
            const float* wrow = a.W1 + (size_t)k * F1 + h * HID;
            const float* a1 = a.as1 + h * HID;
            const float* a2 = a.ad1 + h * HID;
            float s = 0.f, d = 0.f;
#pragma unroll 8
            for (int c = 0; c < HID; ++c) {
                float w = wrow[c];
                s += w * a1[c];
                d += w * a2[c];
            }
            a.w1s[id] = (bf16)s;
            a.w1d[id] = (bf16)d;
        }
    }
    grid.sync();

    // ---- P2: scan (block 0) ----
    if (b == 0) {
        int base = t * 16;
        int local[16];
        int s = 0;
#pragma unroll
        for (int i = 0; i < 16; ++i) { local[i] = s; s += a.counts[base + i]; }
        part[t] = s;
        __syncthreads();
        if (t == 0) {
            int r = 0;
            for (int i = 0; i < 256; ++i) { pre[i] = r; r += part[i]; }
            pre[256] = r;
        }
        __syncthreads();
        int off = pre[t];
#pragma unroll
        for (int i = 0; i < 16; ++i) {
            int v = off + local[i];
            a.row_start[base + i] = v;
            a.cursor[base + i] = v;
        }
        if (t == 0) a.row_start[N_NODES] = pre[256];
    }
    grid.sync();

    // ---- P3: gemm1 (1024, XCD-pinned) | scatter (144) | gemv1 (1024) ----
    for (int u = b; u < P3_TOT; u += gs) {
        if (u < P3_G1) {
            int xx = u & 7, q = u >> 3;           // u%8 == b%8 (gs % 8 == 0)
            int mb = xx * 4 + (q >> 5);
            int nb = q & 31;
            gemm_body<bf16>(a.xb, a.W1T, a.H1, mb * 128, nb * 128, 0, IN_FEAT,
                            F1, IN_FEAT, As, Bs, t);
        } else if (u < P3_G1 + P3_SC) {
            int e = (u - P3_G1) * 256 + t;
            if (e < E_TOT) {
                int d = (e < NE) ? a.edst[e] : (e - NE);
                int slot = atomicAdd(&a.cursor[d], 1);
                a.elist[slot] = e;
            }
        } else {
            int n = (u - P3_G1 - P3_SC) * 4 + wave;
            const float* xr = a.x + (size_t)n * IN_FEAT;
            float s = 0.f, d = 0.f;
            for (int k0 = 0; k0 < IN_FEAT; k0 += 4) {
                f32x4 xv = *(const f32x4*)(xr + k0);
#pragma unroll
                for (int j = 0; j < 4; ++j) {
                    float xs = xv[j];
                    s += xs * (float)a.w1s[(k0 + j) * IN_HEAD + lane];
                    d += xs * (float)a.w1d[(k0 + j) * IN_HEAD + lane];
                }
            }
            a.a_src1[n * IN_HEAD + lane] = s;
            a.a_dst1[n * IN_HEAD + lane] = d;
        }
    }
    grid.sync();

    // ---- P4: agg1, feature-sliced + XCD-pinned (r8), wave-stride over dst ----
    {
        int c = b & 7;                              // slice == XCD
        int wps = (gs >> 3) * 4;                    // waves per slice
        int wIdx = (b >> 3) * 4 + wave;
        int gh = c * 8 + (lane >> 3);
        int sub = lane & 7;
        int fbase = c * 512 + lane * 8;
        for (int d = wIdx; d < N_NODES; d += wps) {
            int beg = a.row_start[d], deg = a.row_start[d + 1] - beg;
            float adst = a.a_dst1[d * IN_HEAD + gh];
            float m = -1e30f, den = 0.f;
            for (int i = sub; i < deg; i += 8) {
                int e = a.elist[beg + i];
                int s = (e < NE) ? a.esrc[e] : d;
                float l = a.a_src1[s * IN_HEAD + gh] + adst;
                l = l > 0.f ? l : NEG_SLOPE * l;
                if (l > m) { den = den * __expf(m - l) + 1.f; m = l; }
                else den += __expf(l - m);
            }
#pragma unroll
            for (int o = 1; o <= 4; o <<= 1) {
                float mo = __shfl_xor(m, o);
                float dno = __shfl_xor(den, o);
                float mn = fmaxf(m, mo);
                den = den * __expf(m - mn) + dno * __expf(mo - mn);
                m = mn;
            }
            float dinv = 1.f / (den + EPS_A);

            float acc[8] = {};
#pragma unroll 2
            for (int i = 0; i < deg; ++i) {
                int e = a.elist[beg + i];
                int s = (e < NE) ? a.esrc[e] : d;
                float l = a.a_src1[s * IN_HEAD + gh] + adst;
                l = l > 0.f ? l : NEG_SLOPE * l;
                float alpha = __expf(l - m) * dinv;
                bf16x8 v = *(const bf16x8*)(a.H1 + (size_t)s * F1 + fbase);
#pragma unroll
                for (int j = 0; j < 8; ++j) acc[j] += alpha * (float)v[j];
            }
            bf16x8 o;
#pragma unroll
            for (int j = 0; j < 8; ++j) {
                float v = acc[j] + a.b1[fbase + j];
                o[j] = (bf16)(v > 0.f ? v : (__expf(v) - 1.f));
            }
            *(bf16x8*)(a.h_elu + (size_t)d * F1 + fbase) = o;
        }
    }
    grid.sync();

    // ---- P5: gemm2 split-K=8 (r11 decode, zb = XCD) ----
    for (int u = b; u < ZSPLIT * 160; u += gs) {
        int xx = u & 7, q = u >> 3;
        int gp = q / 5, nb = q - gp * 5;
        int mb = gp, zb = xx;
        const int kchunk = F1 / ZSPLIT;
        gemm_body<bf16>(a.h_elu, a.W2T, a.Hp + (size_t)zb * N_NODES * F2,
                        mb * 128, nb * 128, zb * kchunk, kchunk,
                        F2, F1, As, Bs, t);
    }
    grid.sync();

    // ---- P6: fold 8 bf16 z-partials -> H2 fp32 + att2 dots ----
    for (int n = b; n < N_NODES; n += gs) {
        if (t < 160) {
            int h = t >> 5;
            f32x4 sum = {};
#pragma unroll
            for (int z = 0; z < ZSPLIT; ++z) {
                bf16x4 v = *(const bf16x4*)(a.Hp + (size_t)z * N_NODES * F2 +
                                            (size_t)n * F2 + t * 4);
                sum[0] += (float)v[0]; sum[1] += (float)v[1];
                sum[2] += (float)v[2]; sum[3] += (float)v[3];
            }
            *(f32x4*)(a.H2 + (size_t)n * F2 + t * 4) = sum;
            f32x4 ws = *(const f32x4*)(a.as2 + t * 4);
            f32x4 wd = *(const f32x4*)(a.ad2 + t * 4);
            float s = sum[0]*ws[0] + sum[1]*ws[1] + sum[2]*ws[2] + sum[3]*ws[3];
            float d = sum[0]*wd[0] + sum[1]*wd[1] + sum[2]*wd[2] + sum[3]*wd[3];
#pragma unroll
            for (int o = 1; o <= 16; o <<= 1) {
                s += __shfl_xor(s, o);
                d += __shfl_xor(d, o);
            }
            if ((t & 31) == 0) {
                a.a_src2[n * OUT_HEAD + h] = s;
                a.a_dst2[n * OUT_HEAD + h] = d;
            }
        }
    }
    grid.sync();

    // ---- P7a: layer-2 softmax stats ----
    for (int id = b * 256 + t; id < N_NODES * OUT_HEAD; id += gs * 256) {
        int d = id / OUT_HEAD, h = id - d * OUT_HEAD;
        int beg = a.row_start[d], deg = a.row_start[d + 1] - beg;
        float adst = a.a_dst2[id];
        float m = -1e30f, den = 0.f;
        for (int i = 0; i < deg; ++i) {
            int e = a.elist[beg + i];
            int s = (e < NE) ? a.esrc[e] : d;
            float l = a.a_src2[s * OUT_HEAD + h] + adst;
            l = l > 0.f ? l : NEG_SLOPE * l;
            if (l > m) { den = den * __expf(m - l) + 1.f; m = l; }
            else den += __expf(l - m);
        }
        a.m2[id] = m;
        a.dinv2[id] = 1.f / (den + EPS_A);
    }
    grid.sync();

    // ---- P7b: edge-parallel beta ----
    for (int id = b * 256 + t; id < E_TOT * OUT_HEAD; id += gs * 256) {
        int e = id / OUT_HEAD, h = id - e * OUT_HEAD;
        int s = (e < NE) ? a.esrc[e] : (e - NE);
        int d = (e < NE) ? a.edst[e] : (e - NE);
        float l = a.a_src2[s * OUT_HEAD + h] + a.a_dst2[d * OUT_HEAD + h];
        l = l > 0.f ? l : NEG_SLOPE * l;
        float alpha = __expf(l - a.m2[d * OUT_HEAD + h]) * a.dinv2[d * OUT_HEAD + h];
        atomicAdd(&a.beta[s * OUT_HEAD + h], alpha);
    }
    grid.sync();

    // ---- P8: weighted column-sum (128 units, striped atomics) ----
    for (int u = b; u < N_NODES / 32; u += gs) {
        int n0 = u * 32;
        int h = t >> 5;
        float a0 = 0.f, a1 = 0.f, a2 = 0.f, a3 = 0.f;
        __syncthreads();   // protect buf reuse
        if (t < 160) {
            for (int i = 0; i < 32; ++i) {
                int s = n0 + i;
                float bh = a.beta[s * OUT_HEAD + h];
                f32x4 v = *(const f32x4*)(a.H2 + (size_t)s * F2 + t * 4);
                a0 += bh * v[0]; a1 += bh * v[1];
                a2 += bh * v[2]; a3 += bh * v[3];
            }
            buf[t * 4 + 0] = a0; buf[t * 4 + 1] = a1;
            buf[t * 4 + 2] = a2; buf[t * 4 + 3] = a3;
        }
        __syncthreads();
        if (t < OUT_FEAT) {
            float s = 0.f;
#pragma unroll
            for (int hh = 0; hh < OUT_HEAD; ++hh) s += buf[hh * OUT_FEAT + t];
            atomicAdd(&a.acc_out[(u & 7) * OUT_FEAT + t], s);
        }
    }
    grid.sync();

    // ---- P9: final tanh (block 0) ----
    if (b == 0 && t < OUT_FEAT) {
        float tot = 0.f;
#pragma unroll
        for (int k = 0; k < 8; ++k) tot += a.acc_out[k * OUT_FEAT + t];
        a.out[t] = tanhf(tot * (1.f / (OUT_HEAD * (float)N_NODES)) + a.b2[t]);
    }
}

// ---------------- launch ----------------
extern "C" void kernel_launch(void* const* d_in, const int* in_sizes, int n_in,
                              void* d_out, int out_size, void* d_ws, size_t ws_size,
                              hipStream_t stream) {
    MegaArgs a;
    a.x   = (const float*)d_in[0];
    const int* ei = (const int*)d_in[1];
    a.W1  = (const float*)d_in[2];
    a.as1 = (const float*)d_in[3];
    a.ad1 = (const float*)d_in[4];
    a.b1  = (const float*)d_in[5];
    a.W2  = (const float*)d_in[6];
    a.as2 = (const float*)d_in[7];
    a.ad2 = (const float*)d_in[8];
    a.b2  = (const float*)d_in[9];
    a.out = (float*)d_out;
    a.esrc = ei;
    a.edst = ei + NE;

    char* p = (char*)d_ws;
    auto bump = [&](size_t bytes) {
        void* r = (void*)p;
        p += (bytes + 255) & ~(size_t)255;
        return r;
    };
    a.H1     = (bf16*)bump((size_t)N_NODES * F1 * 2);          // 32 MB
    a.h_elu  = (bf16*)bump((size_t)N_NODES * F1 * 2);          // 32 MB
    a.H2     = (float*)bump((size_t)N_NODES * F2 * 4);         // 10.5 MB
    a.Hp     = (bf16*)bump((size_t)ZSPLIT * N_NODES * F2 * 2); // 42 MB
    a.xb     = (bf16*)bump((size_t)N_NODES * IN_FEAT * 2);
    a.W1T    = (bf16*)bump((size_t)F1 * IN_FEAT * 2);
    a.W2T    = (bf16*)bump((size_t)F2 * F1 * 2);
    a.w1s    = (bf16*)bump((size_t)IN_FEAT * IN_HEAD * 2);
    a.w1d    = (bf16*)bump((size_t)IN_FEAT * IN_HEAD * 2);
    a.a_src1 = (float*)bump((size_t)N_NODES * IN_HEAD * 4);
    a.a_dst1 = (float*)bump((size_t)N_NODES * IN_HEAD * 4);
    a.a_src2 = (float*)bump((size_t)N_NODES * OUT_HEAD * 4);
    a.a_dst2 = (float*)bump((size_t)N_NODES * OUT_HEAD * 4);
    a.m2     = (float*)bump((size_t)N_NODES * OUT_HEAD * 4);
    a.dinv2  = (float*)bump((size_t)N_NODES * OUT_HEAD * 4);
    a.row_start = (int*)bump((N_NODES + 1) * 4);
    a.cursor = (int*)bump(N_NODES * 4);
    a.elist  = (int*)bump(E_TOT * 4);
    a.counts = (int*)bump((size_t)ZWORDS * 4);
    a.beta    = (float*)(a.counts + N_NODES);
    a.acc_out = a.beta + N_NODES * OUT_HEAD;

    // grid: co-resident capacity (coop requirement), capped at 768, mult of 8
    int maxB = 2;
    hipOccupancyMaxActiveBlocksPerMultiprocessor(&maxB, mega_kernel, 256, 0);
    int grid = maxB * 256;
    if (grid > 768) grid = 768;
    grid = (grid / 8) * 8;
    if (grid < 8) grid = 8;

    void* kargs[] = { &a };
    hipLaunchCooperativeKernel((const void*)mega_kernel, dim3(grid), dim3(256),
                               kargs, 0, stream);
}

// Round 13
// 246.775 us; speedup vs baseline: 2.8947x; 2.8947x over previous
//
#include <hip/hip_runtime.h>
#include <hip/hip_bf16.h>

// ---------------- problem constants ----------------
#define N_NODES 4096
#define NE      32768           // raw edges
#define E_TOT   (NE + N_NODES)  // + self loops = 36864
#define IN_FEAT 256
#define HID     64
#define IN_HEAD 64
#define F1      4096            // IN_HEAD*HID
#define OUT_HEAD 5
#define OUT_FEAT 128
#define F2      640             // OUT_HEAD*OUT_FEAT
#define NEG_SLOPE 0.2f
#define EPS_A   1e-16f
#define ZSPLIT  8               // gemm2 split-K factor (r11-verified)

typedef __bf16 bf16;
typedef bf16 bf16x8 __attribute__((ext_vector_type(8)));
typedef bf16 bf16x4 __attribute__((ext_vector_type(4)));
typedef float f32x4 __attribute__((ext_vector_type(4)));

// async global->LDS, 16B per lane; lds base must be wave-uniform (m104/m108)
__device__ inline void async_cp16(bf16* lds, const bf16* g) {
    __builtin_amdgcn_global_load_lds(
        (const __attribute__((address_space(1))) unsigned int*)g,
        (__attribute__((address_space(3))) unsigned int*)lds, 16, 0, 0);
}

// ---------------- CSR build ----------------
__global__ void hist_kernel(const int* __restrict__ edst, int* counts) {
    int e = blockIdx.x * 256 + threadIdx.x;
    if (e >= E_TOT) return;
    int d = (e < NE) ? edst[e] : (e - NE);
    atomicAdd(&counts[d], 1);
}

__global__ void scan_kernel(const int* __restrict__ counts,
                            int* __restrict__ row_start, int* __restrict__ cursor) {
    __shared__ int part[256];
    __shared__ int pre[257];
    int t = threadIdx.x;
    int base = t * 16;
    int local[16];
    int s = 0;
#pragma unroll
    for (int i = 0; i < 16; ++i) { local[i] = s; s += counts[base + i]; }
    part[t] = s;
    __syncthreads();
    if (t == 0) {
        int r = 0;
        for (int i = 0; i < 256; ++i) { pre[i] = r; r += part[i]; }
        pre[256] = r;
    }
    __syncthreads();
    int off = pre[t];
#pragma unroll
    for (int i = 0; i < 16; ++i) {
        int v = off + local[i];
        row_start[base + i] = v;
        cursor[base + i] = v;
    }
    if (t == 0) row_start[N_NODES] = pre[256];
}

__global__ void scatter_kernel(const int* __restrict__ edst,
                               int* cursor, int* __restrict__ elist) {
    int e = blockIdx.x * 256 + threadIdx.x;
    if (e >= E_TOT) return;
    int d = (e < NE) ? edst[e] : (e - NE);
    int slot = atomicAdd(&cursor[d], 1);
    elist[slot] = e;
}

// ------------- merged operand prep: tobf16(x) | W1^T | W2^T | att-fold ------
#define PB_X   512
#define PB_W1  1024
#define PB_W2  2560
__global__ __launch_bounds__(256)
void prep_kernel(const float* __restrict__ x, bf16* __restrict__ xb,
                 const float* __restrict__ W1, bf16* __restrict__ W1T,
                 const float* __restrict__ W2, bf16* __restrict__ W2T,
                 const float* __restrict__ as1, const float* __restrict__ ad1,
                 bf16* __restrict__ w1s, bf16* __restrict__ w1d) {
    __shared__ float tile[32][33];
    int b = blockIdx.x, t = threadIdx.x;
    if (b < PB_X) {
        int i = b * 256 + t;
        f32x4 a = *(const f32x4*)(x + (size_t)i * 8);
        f32x4 c = *(const f32x4*)(x + (size_t)i * 8 + 4);
        bf16x8 r;
        r[0] = (bf16)a[0]; r[1] = (bf16)a[1]; r[2] = (bf16)a[2]; r[3] = (bf16)a[3];
        r[4] = (bf16)c[0]; r[5] = (bf16)c[1]; r[6] = (bf16)c[2]; r[7] = (bf16)c[3];
        *(bf16x8*)(xb + (size_t)i * 8) = r;
    } else if (b < PB_X + PB_W1 + PB_W2) {
        const float* S; bf16* D; int R, C, gx, gy;
        if (b < PB_X + PB_W1) {
            int bb = b - PB_X;                    // W1: 256 x 4096
            S = W1; D = W1T; R = IN_FEAT; C = F1;
            gx = bb % (F1 / 32); gy = bb / (F1 / 32);
        } else {
            int bb = b - PB_X - PB_W1;            // W2: 4096 x 640
            S = W2; D = W2T; R = F1; C = F2;
            gx = bb % (F2 / 32); gy = bb / (F2 / 32);
        }
        int tx = t & 31, ty = t >> 5;
        int c0 = gx * 32, r0 = gy * 32;
#pragma unroll
        for (int i = 0; i < 4; ++i)
            tile[ty + i * 8][tx] = S[(size_t)(r0 + ty + i * 8) * C + c0 + tx];
        __syncthreads();
#pragma unroll
        for (int i = 0; i < 4; ++i)
            D[(size_t)(c0 + ty + i * 8) * R + r0 + tx] = (bf16)tile[tx][ty + i * 8];
    } else {
        int id = (b - PB_X - PB_W1 - PB_W2) * 256 + t;  // 16384 = 256k x 64h
        int k = id >> 6, h = id & 63;
        const float* wrow = W1 + (size_t)k * F1 + h * HID;
        const float* a1 = as1 + h * HID;
        const float* a2 = ad1 + h * HID;
        float s = 0.f, d = 0.f;
#pragma unroll 8
        for (int c = 0; c < HID; ++c) {
            float w = wrow[c];
            s += w * a1[c];
            d += w * a2[c];
        }
        w1s[id] = (bf16)s;
        w1d[id] = (bf16)d;
    }
}

// ---------------- MFMA GEMM: C[M,N] = A[M,K] @ BT[N,K]^T ----------------
// BM=BN=128, BK=64; XOR-swizzled LDS (0 bank conflicts, verified r4).
// Standalone kernels only (r9/r12: co-dispatching foreign bodies or phases
// shrinks the register budget below the 92 VGPR this body needs -> spills).
template <typename TC>
__device__ __forceinline__ void gemm_body(
    const bf16* __restrict__ A, const bf16* __restrict__ BT, TC* __restrict__ Cz,
    int m0, int n0, int kbeg, int kchunk, int Ncols, int Kdim,
    bf16 (*As)[64], bf16 (*Bs)[64], int tid) {
    const int wave = tid >> 6, lane = tid & 63;
    const int quad = lane >> 4, lr = lane & 15;
    const int wm = (wave >> 1) * 64;
    const int wn = (wave & 1) * 64;
    const int srow = lane >> 3;
    const int scol = ((lane & 7) ^ srow) * 8;
    const int xk = lr & 7;

    f32x4 acc[4][4] = {};

    for (int kk = 0; kk < kchunk; kk += 64) {
        int k0 = kbeg + kk;
#pragma unroll
        for (int c = 0; c < 4; ++c) {
            int r = wave * 32 + c * 8;
            async_cp16(&As[r][0], A + (size_t)(m0 + r + srow) * Kdim + k0 + scol);
            async_cp16(&Bs[r][0], BT + (size_t)(n0 + r + srow) * Kdim + k0 + scol);
        }
        __syncthreads();
#pragma unroll
        for (int ks = 0; ks < 2; ++ks) {
            int ch = ((ks * 4 + quad) ^ xk) * 8;
            bf16x8 af[4], bfr[4];
#pragma unroll
            for (int mt = 0; mt < 4; ++mt)
                af[mt] = *(const bf16x8*)(&As[wm + mt * 16 + lr][ch]);
#pragma unroll
            for (int nt = 0; nt < 4; ++nt)
                bfr[nt] = *(const bf16x8*)(&Bs[wn + nt * 16 + lr][ch]);
#pragma unroll
            for (int mt = 0; mt < 4; ++mt)
#pragma unroll
                for (int nt = 0; nt < 4; ++nt)
                    acc[mt][nt] = __builtin_amdgcn_mfma_f32_16x16x32_bf16(
                        af[mt], bfr[nt], acc[mt][nt], 0, 0, 0);
        }
        __syncthreads();
    }

#pragma unroll
    for (int mt = 0; mt < 4; ++mt)
#pragma unroll
        for (int nt = 0; nt < 4; ++nt) {
            int row0 = m0 + wm + mt * 16 + quad * 4;
            int col = n0 + wn + nt * 16 + lr;
#pragma unroll
            for (int r = 0; r < 4; ++r)
                Cz[(size_t)(row0 + r) * Ncols + col] = (TC)acc[mt][nt][r];
        }
}

// ------------- GEMM1 (r8 grid: 32x32 blocks) --------------------------------
__global__ __launch_bounds__(256)
void gemm1_kernel(const bf16* __restrict__ A, const bf16* __restrict__ BT,
                  bf16* __restrict__ C) {
    __shared__ bf16 As[128][64];
    __shared__ bf16 Bs[128][64];
    gemm_body<bf16>(A, BT, C, blockIdx.y * 128, blockIdx.x * 128, 0, IN_FEAT,
                    F1, IN_FEAT, As, Bs, threadIdx.x);
}

// ------------- GEMM2: split-K=8, 1280 blocks, bf16 z-partials (r11) ---------
// Decode: xx=bid&7 (XCD), q=bid>>3 in [0,160); gp=q/5, nb=q%5; mb=gp, zb=xx.
// Each XCD owns one disjoint 4MB K-slice of A; B-slice 640KB L2-resident;
// 5 consecutive n-blocks reuse each A-tile. Plain bf16 stores (r7: atomics
// on H2 were the 68us limiter).
__global__ __launch_bounds__(256)
void gemm2_kernel(const bf16* __restrict__ A, const bf16* __restrict__ BT,
                  bf16* __restrict__ C) {
    __shared__ bf16 As[128][64];
    __shared__ bf16 Bs[128][64];
    int bid = blockIdx.x;
    int xx = bid & 7, q = bid >> 3;
    int gp = q / 5, nb = q - gp * 5;
    int mb = gp, zb = xx;
    const int kchunk = F1 / ZSPLIT;      // 512
    gemm_body<bf16>(A, BT, C + (size_t)zb * N_NODES * F2,
                    mb * 128, nb * 128, zb * kchunk, kchunk,
                    F2, F1, As, Bs, threadIdx.x);
}

// a_src1[n][h] = x[n,:] @ w1s[:,h]  — wave per node, lane = head
__global__ __launch_bounds__(256)
void gemv1_kernel(const float* __restrict__ x,
                  const bf16* __restrict__ w1s, const bf16* __restrict__ w1d,
                  float* __restrict__ a_src, float* __restrict__ a_dst) {
    int wave = threadIdx.x >> 6, lane = threadIdx.x & 63;
    int n = blockIdx.x * 4 + wave;
    const float* xr = x + (size_t)n * IN_FEAT;
    float s = 0.f, d = 0.f;
    for (int k0 = 0; k0 < IN_FEAT; k0 += 4) {
        f32x4 xv = *(const f32x4*)(xr + k0);   // wave-uniform -> broadcast
#pragma unroll
        for (int j = 0; j < 4; ++j) {
            float xs = xv[j];
            s += xs * (float)w1s[(k0 + j) * IN_HEAD + lane];
            d += xs * (float)w1d[(k0 + j) * IN_HEAD + lane];
        }
    }
    a_src[n * IN_HEAD + lane] = s;
    a_dst[n * IN_HEAD + lane] = d;
}

// ------- layer-1 aggregation, FEATURE-SLICED + XCD-PINNED (r8) --------------
// grid = 4096 dst x 8 slices, 1 wave; bid&7 = slice -> XCD; XCD x touches H1
// cols [512x,512x+512) = 4 MB = its L2 (r7->r8: agg1 51 -> <40 us).
__global__ __launch_bounds__(64)
void agg1_kernel(const int* __restrict__ es, const int* __restrict__ row_start,
                 const int* __restrict__ elist,
                 const float* __restrict__ a_src, const float* __restrict__ a_dst,
                 const bf16* __restrict__ H1, const float* __restrict__ b1,
                 bf16* __restrict__ h_elu) {
    int bid = blockIdx.x;
    int c = bid & 7;            // feature slice / XCD
    int d = bid >> 3;           // dst node
    int lane = threadIdx.x;
    int gh = c * 8 + (lane >> 3);   // global head for this lane
    int sub = lane & 7;
    int beg = row_start[d], deg = row_start[d + 1] - beg;
    float adst = a_dst[d * IN_HEAD + gh];

    // online softmax stats: 8 lanes per head, strided, shuffle-merged
    float m = -1e30f, den = 0.f;
    for (int i = sub; i < deg; i += 8) {
        int e = elist[beg + i];
        int s = (e < NE) ? es[e] : d;
        float l = a_src[s * IN_HEAD + gh] + adst;
        l = l > 0.f ? l : NEG_SLOPE * l;
        if (l > m) { den = den * __expf(m - l) + 1.f; m = l; }
        else den += __expf(l - m);
    }
#pragma unroll
    for (int o = 1; o <= 4; o <<= 1) {   // xor 1,2,4 stays in 8-lane group
        float mo = __shfl_xor(m, o);
        float dno = __shfl_xor(den, o);
        float mn = fmaxf(m, mo);
        den = den * __expf(m - mn) + dno * __expf(mo - mn);
        m = mn;
    }
    float dinv = 1.f / (den + EPS_A);

    // gather: lane reads its 16B of the slice per edge (1 KB/wave/edge)
    int fbase = c * 512 + lane * 8;
    float acc[8] = {};
#pragma unroll 2
    for (int i = 0; i < deg; ++i) {
        int e = elist[beg + i];              // wave-uniform -> broadcast
        int s = (e < NE) ? es[e] : d;
        float l = a_src[s * IN_HEAD + gh] + adst;
        l = l > 0.f ? l : NEG_SLOPE * l;
        float alpha = __expf(l - m) * dinv;
        bf16x8 v = *(const bf16x8*)(H1 + (size_t)s * F1 + fbase);
#pragma unroll
        for (int j = 0; j < 8; ++j) acc[j] += alpha * (float)v[j];
    }

    bf16x8 o;
#pragma unroll
    for (int j = 0; j < 8; ++j) {
        float v = acc[j] + b1[fbase + j];
        o[j] = (bf16)(v > 0.f ? v : (__expf(v) - 1.f));   // ELU
    }
    *(bf16x8*)(h_elu + (size_t)d * F1 + fbase) = o;
}

// ------- fold 8 bf16 z-partials -> H2 fp32, fused att2 dots ----------------
__global__ __launch_bounds__(192)
void fold2_kernel(const bf16* __restrict__ Hp,
                  const float* __restrict__ as2, const float* __restrict__ ad2,
                  float* __restrict__ H2,
                  float* __restrict__ a_src, float* __restrict__ a_dst) {
    int n = blockIdx.x, t = threadIdx.x;
    if (t >= 160) return;
    int h = t >> 5;
    f32x4 sum = {};
#pragma unroll
    for (int z = 0; z < ZSPLIT; ++z) {
        bf16x4 v = *(const bf16x4*)(Hp + (size_t)z * N_NODES * F2 + (size_t)n * F2 + t * 4);
        sum[0] += (float)v[0]; sum[1] += (float)v[1];
        sum[2] += (float)v[2]; sum[3] += (float)v[3];
    }
    *(f32x4*)(H2 + (size_t)n * F2 + t * 4) = sum;
    f32x4 ws = *(const f32x4*)(as2 + t * 4);
    f32x4 wd = *(const f32x4*)(ad2 + t * 4);
    float s = sum[0] * ws[0] + sum[1] * ws[1] + sum[2] * ws[2] + sum[3] * ws[3];
    float d = sum[0] * wd[0] + sum[1] * wd[1] + sum[2] * wd[2] + sum[3] * wd[3];
#pragma unroll
    for (int o = 1; o <= 16; o <<= 1) {
        s += __shfl_xor(s, o);
        d += __shfl_xor(d, o);
    }
    if ((t & 31) == 0) {
        a_src[n * OUT_HEAD + h] = s;
        a_dst[n * OUT_HEAD + h] = d;
    }
}

// ------- layer-2 softmax stats: thread per (dst,head) over CSR --------------
__global__ void stats2_kernel(const int* __restrict__ es,
                              const int* __restrict__ row_start,
                              const int* __restrict__ elist,
                              const float* __restrict__ a_src,
                              const float* __restrict__ a_dst,
                              float* __restrict__ m2, float* __restrict__ dinv2) {
    int id = blockIdx.x * 256 + threadIdx.x;
    if (id >= N_NODES * OUT_HEAD) return;
    int d = id / OUT_HEAD, h = id - d * OUT_HEAD;
    int beg = row_start[d], deg = row_start[d + 1] - beg;
    float adst = a_dst[id];
    float m = -1e30f, den = 0.f;
    for (int i = 0; i < deg; ++i) {
        int e = elist[beg + i];
        int s = (e < NE) ? es[e] : d;
        float l = a_src[s * OUT_HEAD + h] + adst;
        l = l > 0.f ? l : NEG_SLOPE * l;
        if (l > m) { den = den * __expf(m - l) + 1.f; m = l; }
        else den += __expf(l - m);
    }
    m2[id] = m;
    dinv2[id] = 1.f / (den + EPS_A);
}

// ------- beta[s][h] = sum over edges with src s of alpha2[e][h] -------------
__global__ void beta_kernel(const int* __restrict__ es, const int* __restrict__ ed,
                            const float* __restrict__ a_src, const float* __restrict__ a_dst,
                            const float* __restrict__ m2, const float* __restrict__ dinv2,
                            float* __restrict__ beta) {
    int id = blockIdx.x * 256 + threadIdx.x;
    if (id >= E_TOT * OUT_HEAD) return;
    int e = id / OUT_HEAD, h = id - e * OUT_HEAD;
    int s = (e < NE) ? es[e] : (e - NE);
    int d = (e < NE) ? ed[e] : (e - NE);
    float l = a_src[s * OUT_HEAD + h] + a_dst[d * OUT_HEAD + h];
    l = l > 0.f ? l : NEG_SLOPE * l;
    float alpha = __expf(l - m2[d * OUT_HEAD + h]) * dinv2[d * OUT_HEAD + h];
    atomicAdd(&beta[s * OUT_HEAD + h], alpha);
}

// ------- total[c] = sum_s sum_h beta[s,h]H2[s,h*128+c]; 8-way stripes -------
__global__ __launch_bounds__(256)
void wsum_kernel(const float* __restrict__ H2, const float* __restrict__ beta,
                 float* __restrict__ acc_out) {
    __shared__ float buf[F2];
    int t = threadIdx.x;
    int n0 = blockIdx.x * 32;
    int h = t >> 5;
    float a0 = 0.f, a1 = 0.f, a2 = 0.f, a3 = 0.f;
    if (t < 160) {
        for (int i = 0; i < 32; ++i) {
            int s = n0 + i;
            float bh = beta[s * OUT_HEAD + h];
            f32x4 v = *(const f32x4*)(H2 + (size_t)s * F2 + t * 4);
            a0 += bh * v[0]; a1 += bh * v[1];
            a2 += bh * v[2]; a3 += bh * v[3];
        }
        buf[t * 4 + 0] = a0; buf[t * 4 + 1] = a1;
        buf[t * 4 + 2] = a2; buf[t * 4 + 3] = a3;
    }
    __syncthreads();
    if (t < OUT_FEAT) {
        float s = 0.f;
#pragma unroll
        for (int hh = 0; hh < OUT_HEAD; ++hh) s += buf[hh * OUT_FEAT + t];
        atomicAdd(&acc_out[(blockIdx.x & 7) * OUT_FEAT + t], s);
    }
}

// ---------------- final: fold stripes, scale, +b2, tanh ----------------
__global__ void tanh_kernel(const float* __restrict__ acc_out,
                            const float* __restrict__ b2, float* __restrict__ out) {
    int c = threadIdx.x;
    float tot = 0.f;
#pragma unroll
    for (int k = 0; k < 8; ++k) tot += acc_out[k * OUT_FEAT + c];
    out[c] = tanhf(tot * (1.f / (OUT_HEAD * (float)N_NODES)) + b2[c]);
}

// ---------------- launch ----------------
extern "C" void kernel_launch(void* const* d_in, const int* in_sizes, int n_in,
                              void* d_out, int out_size, void* d_ws, size_t ws_size,
                              hipStream_t stream) {
    const float* x        = (const float*)d_in[0];
    const int*   ei       = (const int*)d_in[1];
    const float* W1       = (const float*)d_in[2];
    const float* att_src1 = (const float*)d_in[3];
    const float* att_dst1 = (const float*)d_in[4];
    const float* b1       = (const float*)d_in[5];
    const float* W2       = (const float*)d_in[6];
    const float* att_src2 = (const float*)d_in[7];
    const float* att_dst2 = (const float*)d_in[8];
    const float* b2       = (const float*)d_in[9];
    float* out = (float*)d_out;

    const int* esrc = ei;
    const int* edst = ei + NE;

    // workspace carve (~130 MB of the 256 MiB ws)
    char* p = (char*)d_ws;
    auto bump = [&](size_t bytes) {
        void* r = (void*)p;
        p += (bytes + 255) & ~(size_t)255;
        return r;
    };
    bf16*  H1     = (bf16*)bump((size_t)N_NODES * F1 * 2);          // 32 MB
    bf16*  h_elu  = (bf16*)bump((size_t)N_NODES * F1 * 2);          // 32 MB
    float* H2     = (float*)bump((size_t)N_NODES * F2 * 4);         // 10.5 MB
    bf16*  Hp     = (bf16*)bump((size_t)ZSPLIT * N_NODES * F2 * 2); // 42 MB
    bf16*  xb     = (bf16*)bump((size_t)N_NODES * IN_FEAT * 2);     // 2 MB
    bf16*  W1T    = (bf16*)bump((size_t)F1 * IN_FEAT * 2);          // 2 MB
    bf16*  W2T    = (bf16*)bump((size_t)F2 * F1 * 2);               // 5 MB
    bf16*  w1s    = (bf16*)bump((size_t)IN_FEAT * IN_HEAD * 2);
    bf16*  w1d    = (bf16*)bump((size_t)IN_FEAT * IN_HEAD * 2);
    float* a_src1 = (float*)bump((size_t)N_NODES * IN_HEAD * 4);
    float* a_dst1 = (float*)bump((size_t)N_NODES * IN_HEAD * 4);
    float* a_src2 = (float*)bump((size_t)N_NODES * OUT_HEAD * 4);
    float* a_dst2 = (float*)bump((size_t)N_NODES * OUT_HEAD * 4);
    float* m2     = (float*)bump((size_t)N_NODES * OUT_HEAD * 4);
    float* dinv2  = (float*)bump((size_t)N_NODES * OUT_HEAD * 4);
    int*   row_start = (int*)bump((N_NODES + 1) * 4);
    int*   cursor = (int*)bump(N_NODES * 4);
    int*   elist  = (int*)bump(E_TOT * 4);
    // zeroed region: counts | beta | acc_out (one contiguous memset)
    size_t zbytes = N_NODES * 4 + N_NODES * OUT_HEAD * 4 + 8 * OUT_FEAT * 4;
    int*   counts = (int*)bump(zbytes);
    float* beta    = (float*)((char*)counts + N_NODES * 4);
    float* acc_out = beta + N_NODES * OUT_HEAD;

    hipMemsetAsync(counts, 0, zbytes, stream);

    // CSR
    hist_kernel<<<(E_TOT + 255) / 256, 256, 0, stream>>>(edst, counts);
    scan_kernel<<<1, 256, 0, stream>>>(counts, row_start, cursor);
    scatter_kernel<<<(E_TOT + 255) / 256, 256, 0, stream>>>(edst, cursor, elist);

    // operand prep (merged)
    prep_kernel<<<PB_X + PB_W1 + PB_W2 + 64, 256, 0, stream>>>(
        x, xb, W1, W1T, W2, W2T, att_src1, att_dst1, w1s, w1d);

    // layer 1
    gemm1_kernel<<<dim3(F1 / 128, N_NODES / 128), 256, 0, stream>>>(xb, W1T, H1);
    gemv1_kernel<<<N_NODES / 4, 256, 0, stream>>>(x, w1s, w1d, a_src1, a_dst1);
    agg1_kernel<<<N_NODES * 8, 64, 0, stream>>>(
        esrc, row_start, elist, a_src1, a_dst1, H1, b1, h_elu);

    // layer 2: split-K=8 z-partials + fused fold/att2
    gemm2_kernel<<<ZSPLIT * 160, 256, 0, stream>>>(h_elu, W2T, Hp);
    fold2_kernel<<<N_NODES, 192, 0, stream>>>(
        Hp, att_src2, att_dst2, H2, a_src2, a_dst2);
    stats2_kernel<<<(N_NODES * OUT_HEAD + 255) / 256, 256, 0, stream>>>(
        esrc, row_start, elist, a_src2, a_dst2, m2, dinv2);
    beta_kernel<<<(E_TOT * OUT_HEAD + 255) / 256, 256, 0, stream>>>(
        esrc, edst, a_src2, a_dst2, m2, dinv2, beta);
    wsum_kernel<<<N_NODES / 32, 256, 0, stream>>>(H2, beta, acc_out);

    // final
    tanh_kernel<<<1, OUT_FEAT, 0, stream>>>(acc_out, b2, out);
}